// Round 1
// baseline (31554.480 us; speedup 1.0000x reference)
//
#include <hip/hip_runtime.h>
#include <cstddef>
#include <cstdint>

// ---------------------------------------------------------------------------
// GATv2 x3 layers, fp32 baseline.
// N=10000 nodes, E=160000 edges + N self-loops, H=32 heads, dims 4->128->512->1028
// Strategy: CSR (sorted by dst) built per call; per (layer, head):
//   gemm xl, gemm xr -> logits (wave/edge) -> softmax (wave/node) -> aggregate
//   (block/node, accumulating head mean). fp32 throughout for accuracy.
// ---------------------------------------------------------------------------

#define HEADS 32
#define SLOPE_ATT 0.2f
#define SLOPE_ACT 0.01f

// ---------------- CSR build ----------------

__global__ __launch_bounds__(256) void init_counts_kernel(int* counts, int n) {
  int i = blockIdx.x * 256 + threadIdx.x;
  if (i < n) counts[i] = 1;  // self-loop
}

__global__ __launch_bounds__(256) void count_kernel(const int* __restrict__ dst, int* counts, int E) {
  int e = blockIdx.x * 256 + threadIdx.x;
  if (e < E) atomicAdd(&counts[dst[e]], 1);
}

__global__ __launch_bounds__(1024) void scan_kernel(const int* __restrict__ counts,
                                                    int* __restrict__ row_ptr,
                                                    int* __restrict__ cursor, int n) {
  __shared__ int sums[1024];
  int t = threadIdx.x;
  int per = (n + 1023) >> 10;
  int base = t * per;
  int s = 0;
  for (int i = 0; i < per; i++) { int idx = base + i; if (idx < n) s += counts[idx]; }
  sums[t] = s;
  __syncthreads();
  for (int off = 1; off < 1024; off <<= 1) {
    int v = (t >= off) ? sums[t - off] : 0;
    __syncthreads();
    sums[t] += v;
    __syncthreads();
  }
  int run = (t == 0) ? 0 : sums[t - 1];
  for (int i = 0; i < per; i++) {
    int idx = base + i;
    if (idx < n) { row_ptr[idx] = run; cursor[idx] = run; run += counts[idx]; }
  }
  if (t == 1023) row_ptr[n] = sums[1023];
}

__global__ __launch_bounds__(256) void scatter_edges_kernel(const int* __restrict__ ei, int* cursor,
                                                            int* col_src, int* col_dst, int E) {
  int e = blockIdx.x * 256 + threadIdx.x;
  if (e >= E) return;
  int src = ei[e], dst = ei[E + e];
  int pos = atomicAdd(&cursor[dst], 1);
  col_src[pos] = src;
  col_dst[pos] = dst;
}

__global__ __launch_bounds__(256) void scatter_loops_kernel(int* cursor, int* col_src, int* col_dst, int N) {
  int nid = blockIdx.x * 256 + threadIdx.x;
  if (nid >= N) return;
  int pos = atomicAdd(&cursor[nid], 1);
  col_src[pos] = nid;
  col_dst[pos] = nid;
}

// ---------------- GEMM: out[m,c] = bias[col0+c] + sum_k X[m,k]*W[k,col0+c] ----------------
// 64x64 tile, 256 threads, 4x4 microtile, K staged through LDS in chunks of 16.

#define TS 64
#define KT 16

__global__ __launch_bounds__(256) void gemm_bias(const float* __restrict__ X,
                                                 const float* __restrict__ W,
                                                 const float* __restrict__ bias,
                                                 float* __restrict__ out,
                                                 int M, int K, int C, int ldW, int col0) {
  __shared__ __align__(16) float As[KT][TS + 1];  // [k][m], padded
  __shared__ __align__(16) float Bs[KT][TS];      // [k][n]
  int t = threadIdx.x;
  int tx = t & 15, ty = t >> 4;
  int m0 = blockIdx.y * TS, n0 = blockIdx.x * TS;
  float acc[4][4] = {};

  for (int k0 = 0; k0 < K; k0 += KT) {
    // A: 64 rows x 16 k, thread t loads row t>>2, k-offset (t&3)*4 (float4)
    {
      int row = t >> 2, kk = (t & 3) * 4;
      int m = m0 + row;
      float4 v = make_float4(0.f, 0.f, 0.f, 0.f);
      if (m < M && (k0 + kk) < K)
        v = *(const float4*)(X + (size_t)m * K + k0 + kk);
      As[kk + 0][row] = v.x; As[kk + 1][row] = v.y; As[kk + 2][row] = v.z; As[kk + 3][row] = v.w;
    }
    // B: 16 k x 64 n, thread t loads k=t>>4, n-offset (t&15)*4 (float4)
    {
      int kk = t >> 4, nn = (t & 15) * 4;
      int n = n0 + nn;
      float4 v = make_float4(0.f, 0.f, 0.f, 0.f);
      if ((k0 + kk) < K && n < C)
        v = *(const float4*)(W + (size_t)(k0 + kk) * ldW + col0 + n);
      *(float4*)&Bs[kk][nn] = v;
    }
    __syncthreads();
    int kmax = min(KT, K - k0);
    for (int kk = 0; kk < kmax; kk++) {
      float a[4], b[4];
#pragma unroll
      for (int i = 0; i < 4; i++) a[i] = As[kk][ty * 4 + i];
      float4 bv = *(const float4*)&Bs[kk][tx * 4];
      b[0] = bv.x; b[1] = bv.y; b[2] = bv.z; b[3] = bv.w;
#pragma unroll
      for (int i = 0; i < 4; i++)
#pragma unroll
        for (int j = 0; j < 4; j++) acc[i][j] += a[i] * b[j];
    }
    __syncthreads();
  }

#pragma unroll
  for (int i = 0; i < 4; i++) {
    int m = m0 + ty * 4 + i;
    if (m >= M) break;
#pragma unroll
    for (int j = 0; j < 4; j++) {
      int n = n0 + tx * 4 + j;
      if (n < C) out[(size_t)m * C + n] = acc[i][j] + bias[col0 + n];
    }
  }
}

// ---------------- logits: one wave per sorted edge ----------------

__global__ __launch_bounds__(256) void logits_kernel(const int* __restrict__ col_src,
                                                     const int* __restrict__ col_dst,
                                                     const float* __restrict__ xl,
                                                     const float* __restrict__ xr,
                                                     const float* __restrict__ att,
                                                     float* __restrict__ ebuf, int Etot, int C) {
  int e = blockIdx.x * 4 + (threadIdx.x >> 6);
  int lane = threadIdx.x & 63;
  if (e >= Etot) return;
  int src = col_src[e], dst = col_dst[e];
  const float* pl = xl + (size_t)src * C;
  const float* pr = xr + (size_t)dst * C;
  float sum = 0.f;
  for (int c = lane; c < C; c += 64) {
    float v = pl[c] + pr[c];
    v = (v >= 0.f) ? v : SLOPE_ATT * v;
    sum += att[c] * v;
  }
#pragma unroll
  for (int off = 32; off; off >>= 1) sum += __shfl_down(sum, off, 64);
  if (lane == 0) ebuf[e] = sum;
}

// ---------------- edge softmax: one wave per node ----------------

__global__ __launch_bounds__(256) void softmax_kernel(const int* __restrict__ row_ptr,
                                                      const float* __restrict__ ebuf,
                                                      float* __restrict__ alpha, int N) {
  int node = blockIdx.x * 4 + (threadIdx.x >> 6);
  int lane = threadIdx.x & 63;
  if (node >= N) return;
  int s = row_ptr[node], t = row_ptr[node + 1];
  float m = -1e30f;
  for (int j = s + lane; j < t; j += 64) m = fmaxf(m, ebuf[j]);
#pragma unroll
  for (int off = 32; off; off >>= 1) m = fmaxf(m, __shfl_down(m, off, 64));
  m = __shfl(m, 0, 64);
  float den = 0.f;
  for (int j = s + lane; j < t; j += 64) den += expf(ebuf[j] - m);
#pragma unroll
  for (int off = 32; off; off >>= 1) den += __shfl_down(den, off, 64);
  den = __shfl(den, 0, 64);
  float inv = 1.0f / den;
  for (int j = s + lane; j < t; j += 64) alpha[j] = expf(ebuf[j] - m) * inv;
}

// ---------------- aggregation: one block per node, accumulate heads ----------------

__global__ __launch_bounds__(256) void aggregate_kernel(const int* __restrict__ row_ptr,
                                                        const int* __restrict__ col_src,
                                                        const float* __restrict__ alpha,
                                                        const float* __restrict__ xl,
                                                        float* __restrict__ acc,
                                                        int C, int head) {
  int node = blockIdx.x;
  int s = row_ptr[node], t = row_ptr[node + 1];
  for (int c = threadIdx.x; c < C; c += 256) {
    float sum = 0.f;
    for (int j = s; j < t; j++) sum += alpha[j] * xl[(size_t)col_src[j] * C + c];
    size_t o = (size_t)node * C + c;
    acc[o] = (head == 0) ? sum : acc[o] + sum;
  }
}

// ---------------- finalize: mean over heads + bias (+ leaky relu) ----------------

__global__ __launch_bounds__(256) void finalize_kernel(const float* __restrict__ acc,
                                                       const float* __restrict__ bias,
                                                       float* __restrict__ out,
                                                       int total, int C, int apply_act) {
  int i = blockIdx.x * 256 + threadIdx.x;
  if (i >= total) return;
  int c = i % C;
  float v = acc[i] * (1.0f / 32.0f) + bias[c];
  if (apply_act) v = (v >= 0.f) ? v : SLOPE_ACT * v;
  out[i] = v;
}

// ---------------- host ----------------

static inline size_t align16(size_t x) { return (x + 15) & ~size_t(15); }

extern "C" void kernel_launch(void* const* d_in, const int* in_sizes, int n_in,
                              void* d_out, int out_size, void* d_ws, size_t ws_size,
                              hipStream_t stream) {
  const float* x0 = (const float*)d_in[0];
  const int* ei = (const int*)d_in[1];

  const int N = in_sizes[0] / 4;      // 10000
  const int E = in_sizes[1] / 2;      // 160000
  const int ETOT = E + N;             // 170000

  struct LayerP { const float *Wl, *bl, *Wr, *br, *att, *bias; int fi, fo; };
  LayerP L[3] = {
      {(const float*)d_in[2],  (const float*)d_in[3],  (const float*)d_in[4],
       (const float*)d_in[5],  (const float*)d_in[6],  (const float*)d_in[7],  4, 128},
      {(const float*)d_in[8],  (const float*)d_in[9],  (const float*)d_in[10],
       (const float*)d_in[11], (const float*)d_in[12], (const float*)d_in[13], 128, 512},
      {(const float*)d_in[14], (const float*)d_in[15], (const float*)d_in[16],
       (const float*)d_in[17], (const float*)d_in[18], (const float*)d_in[19], 512, 1028},
  };

  // workspace carve
  char* w = (char*)d_ws;
  auto alloc = [&](size_t bytes) { char* p = w; w += align16(bytes); return p; };
  int* counts   = (int*)alloc((size_t)N * 4);
  int* row_ptr  = (int*)alloc((size_t)(N + 1) * 4);
  int* cursor   = (int*)alloc((size_t)N * 4);
  int* col_src  = (int*)alloc((size_t)ETOT * 4);
  int* col_dst  = (int*)alloc((size_t)ETOT * 4);
  float* ebuf   = (float*)alloc((size_t)ETOT * 4);
  float* abuf   = (float*)alloc((size_t)ETOT * 4);
  float* xlh    = (float*)alloc((size_t)N * 1028 * 4);
  float* xrh    = (float*)alloc((size_t)N * 1028 * 4);
  float* h1     = (float*)alloc((size_t)N * 128 * 4);
  float* h2     = (float*)alloc((size_t)N * 512 * 4);
  float* acc12  = (float*)alloc((size_t)N * 512 * 4);

  // ---- CSR build (dst-sorted) ----
  init_counts_kernel<<<(N + 255) / 256, 256, 0, stream>>>(counts, N);
  count_kernel<<<(E + 255) / 256, 256, 0, stream>>>(ei + E, counts, E);
  scan_kernel<<<1, 1024, 0, stream>>>(counts, row_ptr, cursor, N);
  scatter_edges_kernel<<<(E + 255) / 256, 256, 0, stream>>>(ei, cursor, col_src, col_dst, E);
  scatter_loops_kernel<<<(N + 255) / 256, 256, 0, stream>>>(cursor, col_src, col_dst, N);

  const float* x_in[3] = {x0, h1, h2};
  float* layer_out[3]  = {h1, h2, (float*)d_out};
  float* layer_acc[3]  = {acc12, acc12, (float*)d_out};

  for (int l = 0; l < 3; l++) {
    int fi = L[l].fi, C = L[l].fo, ldW = HEADS * C;
    dim3 ggrid((C + TS - 1) / TS, (N + TS - 1) / TS);
    float* acc = layer_acc[l];
    for (int h = 0; h < HEADS; h++) {
      int col0 = h * C;
      gemm_bias<<<ggrid, 256, 0, stream>>>(x_in[l], L[l].Wl, L[l].bl, xlh, N, fi, C, ldW, col0);
      gemm_bias<<<ggrid, 256, 0, stream>>>(x_in[l], L[l].Wr, L[l].br, xrh, N, fi, C, ldW, col0);
      logits_kernel<<<(ETOT + 3) / 4, 256, 0, stream>>>(col_src, col_dst, xlh, xrh,
                                                        L[l].att + (size_t)h * C, ebuf, ETOT, C);
      softmax_kernel<<<(N + 3) / 4, 256, 0, stream>>>(row_ptr, ebuf, abuf, N);
      aggregate_kernel<<<N, 256, 0, stream>>>(row_ptr, col_src, abuf, xlh, acc, C, h);
    }
    finalize_kernel<<<((size_t)N * C + 255) / 256, 256, 0, stream>>>(acc, L[l].bias, layer_out[l],
                                                                     N * C, C, l < 2 ? 1 : 0);
  }
}

// Round 2
// 24305.807 us; speedup vs baseline: 1.2982x; 1.2982x over previous
//
#include <hip/hip_runtime.h>
#include <cstddef>
#include <cstdint>

// ---------------------------------------------------------------------------
// GATv2 x3 layers, fp32. R1: 128x128 fp32 GEMM (aligned ds_read_b128, 8x8
// microtile as 4x 4x4 blocks), float4 logits, fused softmax+aggregate.
// ---------------------------------------------------------------------------

#define HEADS 32
#define SLOPE_ATT 0.2f
#define SLOPE_ACT 0.01f

// ---------------- CSR build ----------------

__global__ __launch_bounds__(256) void init_counts_kernel(int* counts, int n) {
  int i = blockIdx.x * 256 + threadIdx.x;
  if (i < n) counts[i] = 1;  // self-loop
}

__global__ __launch_bounds__(256) void count_kernel(const int* __restrict__ dst, int* counts, int E) {
  int e = blockIdx.x * 256 + threadIdx.x;
  if (e < E) atomicAdd(&counts[dst[e]], 1);
}

__global__ __launch_bounds__(1024) void scan_kernel(const int* __restrict__ counts,
                                                    int* __restrict__ row_ptr,
                                                    int* __restrict__ cursor, int n) {
  __shared__ int sums[1024];
  int t = threadIdx.x;
  int per = (n + 1023) >> 10;
  int base = t * per;
  int s = 0;
  for (int i = 0; i < per; i++) { int idx = base + i; if (idx < n) s += counts[idx]; }
  sums[t] = s;
  __syncthreads();
  for (int off = 1; off < 1024; off <<= 1) {
    int v = (t >= off) ? sums[t - off] : 0;
    __syncthreads();
    sums[t] += v;
    __syncthreads();
  }
  int run = (t == 0) ? 0 : sums[t - 1];
  for (int i = 0; i < per; i++) {
    int idx = base + i;
    if (idx < n) { row_ptr[idx] = run; cursor[idx] = run; run += counts[idx]; }
  }
  if (t == 1023) row_ptr[n] = sums[1023];
}

__global__ __launch_bounds__(256) void scatter_edges_kernel(const int* __restrict__ ei, int* cursor,
                                                            int* col_src, int* col_dst, int E) {
  int e = blockIdx.x * 256 + threadIdx.x;
  if (e >= E) return;
  int src = ei[e], dst = ei[E + e];
  int pos = atomicAdd(&cursor[dst], 1);
  col_src[pos] = src;
  col_dst[pos] = dst;
}

__global__ __launch_bounds__(256) void scatter_loops_kernel(int* cursor, int* col_src, int* col_dst, int N) {
  int nid = blockIdx.x * 256 + threadIdx.x;
  if (nid >= N) return;
  int pos = atomicAdd(&cursor[nid], 1);
  col_src[pos] = nid;
  col_dst[pos] = nid;
}

// ---------------- GEMM 128x128, 256 threads, 8x8 microtile ----------------
// out[m, n] = bias[col0+n] + sum_k X[m,k] * W[k, col0+n]   for n in [0, C)
// blockIdx.z selects (Wl, bl, outL) vs (Wr, br, outR).

#define BM 128
#define BN 128
#define BK 16
#define LDA (BM + 4)  // 132 floats: 528B rows, 16B-aligned, breaks p2 bank stride
#define LDB (BN + 4)

__global__ __launch_bounds__(256) void gemm128(const float* __restrict__ X,
                                               const float* __restrict__ Wl,
                                               const float* __restrict__ Wr,
                                               const float* __restrict__ bl,
                                               const float* __restrict__ br,
                                               float* __restrict__ outL,
                                               float* __restrict__ outR,
                                               int M, int K, int C, int ldW, int col0) {
  const float* W = blockIdx.z ? Wr : Wl;
  const float* bias = blockIdx.z ? br : bl;
  float* out = blockIdx.z ? outR : outL;

  __shared__ __align__(16) float As[BK][LDA];  // [k][m]
  __shared__ __align__(16) float Bs[BK][LDB];  // [k][n]

  int t = threadIdx.x;
  int tx = t & 15, ty = t >> 4;
  int m0 = blockIdx.y * BM, n0 = blockIdx.x * BN;

  float acc00[4][4] = {}, acc01[4][4] = {}, acc10[4][4] = {}, acc11[4][4] = {};

  for (int k0 = 0; k0 < K; k0 += BK) {
    // --- stage A: 128 rows x 16 k. thread t: row (t>>2)+p*64, k-off (t&3)*4
    {
      int kk = (t & 3) * 4;
#pragma unroll
      for (int p = 0; p < 2; p++) {
        int row = (t >> 2) + p * 64;
        int m = m0 + row;
        float4 v = make_float4(0.f, 0.f, 0.f, 0.f);
        if (m < M && (k0 + kk) < K)  // K % 4 == 0 always
          v = *(const float4*)(X + (size_t)m * K + k0 + kk);
        As[kk + 0][row] = v.x; As[kk + 1][row] = v.y;
        As[kk + 2][row] = v.z; As[kk + 3][row] = v.w;
      }
    }
    // --- stage B: 16 k x 128 n. thread t: k = t>>4, col (t&15)*4 + q*64
    {
      int kk = t >> 4;
#pragma unroll
      for (int q = 0; q < 2; q++) {
        int cn = (t & 15) * 4 + q * 64;
        int n = n0 + cn;
        float4 v = make_float4(0.f, 0.f, 0.f, 0.f);
        if ((k0 + kk) < K) {
          if (n + 3 < C) {
            v = *(const float4*)(W + (size_t)(k0 + kk) * ldW + col0 + n);
          } else if (n < C) {
            const float* p = W + (size_t)(k0 + kk) * ldW + col0;
            v.x = p[n];
            v.y = (n + 1 < C) ? p[n + 1] : 0.f;
            v.z = (n + 2 < C) ? p[n + 2] : 0.f;
          }
        }
        *(float4*)&Bs[kk][cn] = v;
      }
    }
    __syncthreads();

    int kmax = min(BK, K - k0);
    for (int kk = 0; kk < kmax; kk++) {
      float4 a0 = *(const float4*)&As[kk][ty * 4];
      float4 a1 = *(const float4*)&As[kk][64 + ty * 4];
      float4 b0 = *(const float4*)&Bs[kk][tx * 4];
      float4 b1 = *(const float4*)&Bs[kk][64 + tx * 4];
      float af0[4] = {a0.x, a0.y, a0.z, a0.w};
      float af1[4] = {a1.x, a1.y, a1.z, a1.w};
      float bf0[4] = {b0.x, b0.y, b0.z, b0.w};
      float bf1[4] = {b1.x, b1.y, b1.z, b1.w};
#pragma unroll
      for (int i = 0; i < 4; i++)
#pragma unroll
        for (int j = 0; j < 4; j++) {
          acc00[i][j] += af0[i] * bf0[j];
          acc01[i][j] += af0[i] * bf1[j];
          acc10[i][j] += af1[i] * bf0[j];
          acc11[i][j] += af1[i] * bf1[j];
        }
    }
    __syncthreads();
  }

  // --- epilogue
#pragma unroll
  for (int ma = 0; ma < 2; ma++) {
#pragma unroll
    for (int i = 0; i < 4; i++) {
      int m = m0 + ma * 64 + ty * 4 + i;
      if (m >= M) continue;
#pragma unroll
      for (int nb = 0; nb < 2; nb++) {
        int n = n0 + nb * 64 + tx * 4;
        float (*blk)[4] = (ma == 0) ? ((nb == 0) ? acc00 : acc01)
                                    : ((nb == 0) ? acc10 : acc11);
        if (n + 3 < C) {
          float4 bv = *(const float4*)(bias + col0 + n);
          float4 o = make_float4(blk[i][0] + bv.x, blk[i][1] + bv.y,
                                 blk[i][2] + bv.z, blk[i][3] + bv.w);
          *(float4*)(out + (size_t)m * C + n) = o;
        } else {
#pragma unroll
          for (int j = 0; j < 4; j++)
            if (n + j < C) out[(size_t)m * C + n + j] = blk[i][j] + bias[col0 + n + j];
        }
      }
    }
  }
}

// ---------------- logits: one wave per sorted edge, float4 ----------------

__global__ __launch_bounds__(256) void logits_kernel(const int* __restrict__ col_src,
                                                     const int* __restrict__ col_dst,
                                                     const float* __restrict__ xl,
                                                     const float* __restrict__ xr,
                                                     const float* __restrict__ att,
                                                     float* __restrict__ ebuf, int Etot, int C) {
  int e = blockIdx.x * 4 + (threadIdx.x >> 6);
  int lane = threadIdx.x & 63;
  if (e >= Etot) return;
  int src = col_src[e], dst = col_dst[e];
  const float* pl = xl + (size_t)src * C;
  const float* pr = xr + (size_t)dst * C;
  int C4 = C >> 2;  // C % 4 == 0 for all layers
  float sum = 0.f;
  for (int c4 = lane; c4 < C4; c4 += 64) {
    int c = c4 * 4;
    float4 l4 = *(const float4*)(pl + c);
    float4 r4 = *(const float4*)(pr + c);
    float4 a4 = *(const float4*)(att + c);
    float v;
    v = l4.x + r4.x; v = (v >= 0.f) ? v : SLOPE_ATT * v; sum += a4.x * v;
    v = l4.y + r4.y; v = (v >= 0.f) ? v : SLOPE_ATT * v; sum += a4.y * v;
    v = l4.z + r4.z; v = (v >= 0.f) ? v : SLOPE_ATT * v; sum += a4.z * v;
    v = l4.w + r4.w; v = (v >= 0.f) ? v : SLOPE_ATT * v; sum += a4.w * v;
  }
#pragma unroll
  for (int off = 32; off; off >>= 1) sum += __shfl_down(sum, off, 64);
  if (lane == 0) ebuf[e] = sum;
}

// ---------------- fused edge-softmax + aggregation: block per node ----------------

#define MAXE 2048

__global__ __launch_bounds__(256) void smax_agg_kernel(const int* __restrict__ row_ptr,
                                                       const int* __restrict__ col_src,
                                                       const float* __restrict__ ebuf,
                                                       const float* __restrict__ xl,
                                                       float* __restrict__ acc,
                                                       int C, int head) {
  int node = blockIdx.x;
  int s = row_ptr[node], t = row_ptr[node + 1];
  int deg = t - s;
  bool fast = (deg <= MAXE);

  __shared__ float sa[MAXE];  // exp(e - m)
  __shared__ int ss[MAXE];    // src ids
  __shared__ float rbuf[8];

  int tid = threadIdx.x;
  int wave = tid >> 6, lane = tid & 63;

  // pass 1: max
  float m = -1e30f;
  for (int j = s + tid; j < t; j += 256) m = fmaxf(m, ebuf[j]);
#pragma unroll
  for (int off = 32; off; off >>= 1) m = fmaxf(m, __shfl_down(m, off, 64));
  if (lane == 0) rbuf[wave] = m;
  __syncthreads();
  m = fmaxf(fmaxf(rbuf[0], rbuf[1]), fmaxf(rbuf[2], rbuf[3]));

  // pass 2: exp + denominator (+ stage src)
  float den = 0.f;
  for (int j = s + tid; j < t; j += 256) {
    float p = expf(ebuf[j] - m);
    den += p;
    if (fast) { sa[j - s] = p; ss[j - s] = col_src[j]; }
  }
#pragma unroll
  for (int off = 32; off; off >>= 1) den += __shfl_down(den, off, 64);
  if (lane == 0) rbuf[4 + wave] = den;
  __syncthreads();
  den = (rbuf[4] + rbuf[5]) + (rbuf[6] + rbuf[7]);
  float inv = 1.0f / den;

  // pass 3: weighted aggregation over channels
  for (int c = tid; c < C; c += 256) {
    float sum = 0.f;
    if (fast) {
      for (int jj = 0; jj < deg; jj++)
        sum += sa[jj] * xl[(size_t)ss[jj] * C + c];
    } else {
      for (int j = s; j < t; j++)
        sum += expf(ebuf[j] - m) * xl[(size_t)col_src[j] * C + c];
    }
    float val = sum * inv;
    size_t o = (size_t)node * C + c;
    acc[o] = (head == 0) ? val : acc[o] + val;
  }
}

// ---------------- finalize: mean over heads + bias (+ leaky relu) ----------------

__global__ __launch_bounds__(256) void finalize_kernel(const float* __restrict__ acc,
                                                       const float* __restrict__ bias,
                                                       float* __restrict__ out,
                                                       int total, int C, int apply_act) {
  int i = blockIdx.x * 256 + threadIdx.x;
  if (i >= total) return;
  int c = i % C;
  float v = acc[i] * (1.0f / 32.0f) + bias[c];
  if (apply_act) v = (v >= 0.f) ? v : SLOPE_ACT * v;
  out[i] = v;
}

// ---------------- host ----------------

static inline size_t align16(size_t x) { return (x + 15) & ~size_t(15); }

extern "C" void kernel_launch(void* const* d_in, const int* in_sizes, int n_in,
                              void* d_out, int out_size, void* d_ws, size_t ws_size,
                              hipStream_t stream) {
  const float* x0 = (const float*)d_in[0];
  const int* ei = (const int*)d_in[1];

  const int N = in_sizes[0] / 4;      // 10000
  const int E = in_sizes[1] / 2;      // 160000
  const int ETOT = E + N;             // 170000

  struct LayerP { const float *Wl, *bl, *Wr, *br, *att, *bias; int fi, fo; };
  LayerP L[3] = {
      {(const float*)d_in[2],  (const float*)d_in[3],  (const float*)d_in[4],
       (const float*)d_in[5],  (const float*)d_in[6],  (const float*)d_in[7],  4, 128},
      {(const float*)d_in[8],  (const float*)d_in[9],  (const float*)d_in[10],
       (const float*)d_in[11], (const float*)d_in[12], (const float*)d_in[13], 128, 512},
      {(const float*)d_in[14], (const float*)d_in[15], (const float*)d_in[16],
       (const float*)d_in[17], (const float*)d_in[18], (const float*)d_in[19], 512, 1028},
  };

  // workspace carve
  char* w = (char*)d_ws;
  auto alloc = [&](size_t bytes) { char* p = w; w += align16(bytes); return p; };
  int* counts   = (int*)alloc((size_t)N * 4);
  int* row_ptr  = (int*)alloc((size_t)(N + 1) * 4);
  int* cursor   = (int*)alloc((size_t)N * 4);
  int* col_src  = (int*)alloc((size_t)ETOT * 4);
  int* col_dst  = (int*)alloc((size_t)ETOT * 4);
  float* ebuf   = (float*)alloc((size_t)ETOT * 4);
  float* xlh    = (float*)alloc((size_t)N * 1028 * 4);
  float* xrh    = (float*)alloc((size_t)N * 1028 * 4);
  float* h1     = (float*)alloc((size_t)N * 128 * 4);
  float* h2     = (float*)alloc((size_t)N * 512 * 4);
  float* acc12  = (float*)alloc((size_t)N * 512 * 4);

  // ---- CSR build (dst-sorted) ----
  init_counts_kernel<<<(N + 255) / 256, 256, 0, stream>>>(counts, N);
  count_kernel<<<(E + 255) / 256, 256, 0, stream>>>(ei + E, counts, E);
  scan_kernel<<<1, 1024, 0, stream>>>(counts, row_ptr, cursor, N);
  scatter_edges_kernel<<<(E + 255) / 256, 256, 0, stream>>>(ei, cursor, col_src, col_dst, E);
  scatter_loops_kernel<<<(N + 255) / 256, 256, 0, stream>>>(cursor, col_src, col_dst, N);

  const float* x_in[3] = {x0, h1, h2};
  float* layer_out[3]  = {h1, h2, (float*)d_out};
  float* layer_acc[3]  = {acc12, acc12, (float*)d_out};

  for (int l = 0; l < 3; l++) {
    int fi = L[l].fi, C = L[l].fo, ldW = HEADS * C;
    dim3 ggrid((C + BN - 1) / BN, (N + BM - 1) / BM, 2);
    float* acc = layer_acc[l];
    for (int h = 0; h < HEADS; h++) {
      int col0 = h * C;
      gemm128<<<ggrid, 256, 0, stream>>>(x_in[l], L[l].Wl, L[l].Wr, L[l].bl, L[l].br,
                                         xlh, xrh, N, fi, C, ldW, col0);
      logits_kernel<<<(ETOT + 3) / 4, 256, 0, stream>>>(col_src, col_dst, xlh, xrh,
                                                        L[l].att + (size_t)h * C, ebuf, ETOT, C);
      smax_agg_kernel<<<N, 256, 0, stream>>>(row_ptr, col_src, ebuf, xlh, acc, C, h);
    }
    finalize_kernel<<<((size_t)N * C + 255) / 256, 256, 0, stream>>>(acc, L[l].bias, layer_out[l],
                                                                     N * C, C, l < 2 ? 1 : 0);
  }
}

// Round 3
// 19129.784 us; speedup vs baseline: 1.6495x; 1.2706x over previous
//
#include <hip/hip_runtime.h>
#include <cstddef>
#include <cstdint>

// ---------------------------------------------------------------------------
// GATv2 x3 layers. R2: layers 2-3 GEMM via split-bf16 MFMA (3x
// v_mfma_f32_32x32x16_bf16: hi*hi + hi*lo + lo*hi, fp32 accum).
// X pre-packed per layer into frag-major bf16 hi/lo; W converted on the fly.
// Layer 1 (K=4) stays on the fp32 128x128 GEMM. Edge phase unchanged from R1.
// ---------------------------------------------------------------------------

#define HEADS 32
#define SLOPE_ATT 0.2f
#define SLOPE_ACT 0.01f

typedef __bf16 bf16_t;
typedef __bf16 bf16x8 __attribute__((ext_vector_type(8)));
typedef float f32x16 __attribute__((ext_vector_type(16)));

// ---------------- CSR build ----------------

__global__ __launch_bounds__(256) void init_counts_kernel(int* counts, int n) {
  int i = blockIdx.x * 256 + threadIdx.x;
  if (i < n) counts[i] = 1;  // self-loop
}

__global__ __launch_bounds__(256) void count_kernel(const int* __restrict__ dst, int* counts, int E) {
  int e = blockIdx.x * 256 + threadIdx.x;
  if (e < E) atomicAdd(&counts[dst[e]], 1);
}

__global__ __launch_bounds__(1024) void scan_kernel(const int* __restrict__ counts,
                                                    int* __restrict__ row_ptr,
                                                    int* __restrict__ cursor, int n) {
  __shared__ int sums[1024];
  int t = threadIdx.x;
  int per = (n + 1023) >> 10;
  int base = t * per;
  int s = 0;
  for (int i = 0; i < per; i++) { int idx = base + i; if (idx < n) s += counts[idx]; }
  sums[t] = s;
  __syncthreads();
  for (int off = 1; off < 1024; off <<= 1) {
    int v = (t >= off) ? sums[t - off] : 0;
    __syncthreads();
    sums[t] += v;
    __syncthreads();
  }
  int run = (t == 0) ? 0 : sums[t - 1];
  for (int i = 0; i < per; i++) {
    int idx = base + i;
    if (idx < n) { row_ptr[idx] = run; cursor[idx] = run; run += counts[idx]; }
  }
  if (t == 1023) row_ptr[n] = sums[1023];
}

__global__ __launch_bounds__(256) void scatter_edges_kernel(const int* __restrict__ ei, int* cursor,
                                                            int* col_src, int* col_dst, int E) {
  int e = blockIdx.x * 256 + threadIdx.x;
  if (e >= E) return;
  int src = ei[e], dst = ei[E + e];
  int pos = atomicAdd(&cursor[dst], 1);
  col_src[pos] = src;
  col_dst[pos] = dst;
}

__global__ __launch_bounds__(256) void scatter_loops_kernel(int* cursor, int* col_src, int* col_dst, int N) {
  int nid = blockIdx.x * 256 + threadIdx.x;
  if (nid >= N) return;
  int pos = atomicAdd(&cursor[nid], 1);
  col_src[pos] = nid;
  col_dst[pos] = nid;
}

// ---------------- split-bf16 pack: X[M,K] fp32 -> frag-major hi/lo ----------------
// pack index: (mtile*(K/8) + kchunk)*1024 + mlocal*8 + (k&7); Mpad = mtiles*128.

__global__ __launch_bounds__(256) void cvt_pack_kernel(const float* __restrict__ X,
                                                       bf16_t* __restrict__ hi,
                                                       bf16_t* __restrict__ lo,
                                                       int M, int Mpad, int K) {
  int t = blockIdx.x * 256 + threadIdx.x;
  int kchunks = K >> 3;
  int total = Mpad * kchunks;
  if (t >= total) return;
  int kc = t % kchunks;
  int m = t / kchunks;
  int mt = m >> 7, ml = m & 127;
  size_t o = ((size_t)(mt * kchunks + kc)) * 1024 + (size_t)ml * 8;
  float v[8];
  if (m < M) {
    float4 a = *(const float4*)(X + (size_t)m * K + kc * 8);
    float4 b = *(const float4*)(X + (size_t)m * K + kc * 8 + 4);
    v[0] = a.x; v[1] = a.y; v[2] = a.z; v[3] = a.w;
    v[4] = b.x; v[5] = b.y; v[6] = b.z; v[7] = b.w;
  } else {
#pragma unroll
    for (int i = 0; i < 8; i++) v[i] = 0.f;
  }
  union { bf16_t h[8]; float4 f; } uh, ul;
#pragma unroll
  for (int i = 0; i < 8; i++) {
    bf16_t h = (bf16_t)v[i];
    uh.h[i] = h;
    ul.h[i] = (bf16_t)(v[i] - (float)h);
  }
  *(float4*)(hi + o) = uh.f;
  *(float4*)(lo + o) = ul.f;
}

// ---------------- MFMA GEMM 128x128, 256 thr, split-bf16 ----------------
// out[m,n] = bias[col0+n] + sum_k X[m,k]*W[k,col0+n], n in [0,C). z: l/r.
// K must be a multiple of 32 (layers 2,3: 128, 512).

__global__ __launch_bounds__(256) void gemm_mfma(const bf16_t* __restrict__ Xh,
                                                 const bf16_t* __restrict__ Xl,
                                                 const float* __restrict__ Wl,
                                                 const float* __restrict__ Wr,
                                                 const float* __restrict__ bl,
                                                 const float* __restrict__ br,
                                                 float* __restrict__ outL,
                                                 float* __restrict__ outR,
                                                 int M, int K, int C, int ldW, int col0) {
  const float* W = blockIdx.z ? Wr : Wl;
  const float* bias = blockIdx.z ? br : bl;
  float* out = blockIdx.z ? outR : outL;

  __shared__ __align__(16) bf16_t AsH[4 * 128 * 8];
  __shared__ __align__(16) bf16_t AsL[4 * 128 * 8];
  __shared__ __align__(16) bf16_t BsH[4 * 128 * 8];
  __shared__ __align__(16) bf16_t BsL[4 * 128 * 8];

  int tid = threadIdx.x;
  int wave = tid >> 6, lane = tid & 63;
  int l31 = lane & 31, lhalf = lane >> 5;
  int mt = blockIdx.y;
  int ntb = blockIdx.x * 128;
  int m0 = mt * 128;

  const bf16_t* Ah = Xh + (size_t)mt * K * 128;
  const bf16_t* Al = Xl + (size_t)mt * K * 128;

  f32x16 acc[4];
  for (int i = 0; i < 4; i++)
    for (int r = 0; r < 16; r++) acc[i][r] = 0.f;

  const bool fullB = (ntb + 128 <= C);

  for (int k0 = 0; k0 < K; k0 += 32) {
    // --- A staging: 4 chunks x 128 rows x 8 bf16 (16B frags), coalesced
#pragma unroll
    for (int r = 0; r < 2; r++) {
      int a = tid + 256 * r;
      int c = a >> 7, mA = a & 127;
      size_t off = ((size_t)((k0 >> 3) + c)) * 1024 + (size_t)mA * 8;
      int li = (c * 128 + mA) * 8;
      *(float4*)&AsH[li] = *(const float4*)(Ah + off);
      *(float4*)&AsL[li] = *(const float4*)(Al + off);
    }
    // --- B staging: read W fp32 rows, split, transpose into frag-major
    {
      int k = tid >> 3;
      int n0 = (tid & 7) * 16;
      const float* wrow = W + (size_t)(k0 + k) * ldW + col0 + ntb;
      int cb = k >> 3, kb = k & 7;
      if (fullB) {
#pragma unroll
        for (int j4 = 0; j4 < 16; j4 += 4) {
          float4 v4 = *(const float4*)(wrow + n0 + j4);
          float vv[4] = {v4.x, v4.y, v4.z, v4.w};
#pragma unroll
          for (int j = 0; j < 4; j++) {
            int n = n0 + j4 + j;
            bf16_t h = (bf16_t)vv[j];
            int idx = (cb * 128 + n) * 8 + kb;
            BsH[idx] = h;
            BsL[idx] = (bf16_t)(vv[j] - (float)h);
          }
        }
      } else {
#pragma unroll
        for (int j = 0; j < 16; j++) {
          int n = n0 + j;
          float v = (ntb + n < C) ? wrow[n] : 0.f;
          bf16_t h = (bf16_t)v;
          int idx = (cb * 128 + n) * 8 + kb;
          BsH[idx] = h;
          BsL[idx] = (bf16_t)(v - (float)h);
        }
      }
    }
    __syncthreads();

    // --- compute: 2 k16-steps, wave owns 32-row band, 4 n-tiles of 32
#pragma unroll
    for (int s = 0; s < 2; s++) {
      int c = s * 2 + lhalf;
      int abase = (c * 128 + wave * 32 + l31) * 8;
      bf16x8 ah = *(const bf16x8*)&AsH[abase];
      bf16x8 al = *(const bf16x8*)&AsL[abase];
#pragma unroll
      for (int nt = 0; nt < 4; nt++) {
        int bbase = (c * 128 + nt * 32 + l31) * 8;
        bf16x8 bh = *(const bf16x8*)&BsH[bbase];
        bf16x8 blo = *(const bf16x8*)&BsL[bbase];
        acc[nt] = __builtin_amdgcn_mfma_f32_32x32x16_bf16(ah, bh, acc[nt], 0, 0, 0);
        acc[nt] = __builtin_amdgcn_mfma_f32_32x32x16_bf16(ah, blo, acc[nt], 0, 0, 0);
        acc[nt] = __builtin_amdgcn_mfma_f32_32x32x16_bf16(al, bh, acc[nt], 0, 0, 0);
      }
    }
    __syncthreads();
  }

  // --- epilogue: C/D layout col=lane&31, row=(r&3)+8*(r>>2)+4*(lane>>5)
#pragma unroll
  for (int nt = 0; nt < 4; nt++) {
    int n = ntb + nt * 32 + l31;
    if (n >= C) continue;
    float bv = bias[col0 + n];
#pragma unroll
    for (int r = 0; r < 16; r++) {
      int row = (r & 3) + 8 * (r >> 2) + 4 * lhalf;
      int m = m0 + wave * 32 + row;
      if (m < M) out[(size_t)m * C + n] = acc[nt][r] + bv;
    }
  }
}

// ---------------- fp32 GEMM (layer 1, K=4) ----------------

#define BM 128
#define BN 128
#define BK 16
#define LDA (BM + 4)
#define LDB (BN + 4)

__global__ __launch_bounds__(256) void gemm128(const float* __restrict__ X,
                                               const float* __restrict__ Wl,
                                               const float* __restrict__ Wr,
                                               const float* __restrict__ bl,
                                               const float* __restrict__ br,
                                               float* __restrict__ outL,
                                               float* __restrict__ outR,
                                               int M, int K, int C, int ldW, int col0) {
  const float* W = blockIdx.z ? Wr : Wl;
  const float* bias = blockIdx.z ? br : bl;
  float* out = blockIdx.z ? outR : outL;

  __shared__ __align__(16) float As[BK][LDA];
  __shared__ __align__(16) float Bs[BK][LDB];

  int t = threadIdx.x;
  int tx = t & 15, ty = t >> 4;
  int m0 = blockIdx.y * BM, n0 = blockIdx.x * BN;

  float acc00[4][4] = {}, acc01[4][4] = {}, acc10[4][4] = {}, acc11[4][4] = {};

  for (int k0 = 0; k0 < K; k0 += BK) {
    {
      int kk = (t & 3) * 4;
#pragma unroll
      for (int p = 0; p < 2; p++) {
        int row = (t >> 2) + p * 64;
        int m = m0 + row;
        float4 v = make_float4(0.f, 0.f, 0.f, 0.f);
        if (m < M && (k0 + kk) < K)
          v = *(const float4*)(X + (size_t)m * K + k0 + kk);
        As[kk + 0][row] = v.x; As[kk + 1][row] = v.y;
        As[kk + 2][row] = v.z; As[kk + 3][row] = v.w;
      }
    }
    {
      int kk = t >> 4;
#pragma unroll
      for (int q = 0; q < 2; q++) {
        int cn = (t & 15) * 4 + q * 64;
        int n = n0 + cn;
        float4 v = make_float4(0.f, 0.f, 0.f, 0.f);
        if ((k0 + kk) < K) {
          if (n + 3 < C) {
            v = *(const float4*)(W + (size_t)(k0 + kk) * ldW + col0 + n);
          } else if (n < C) {
            const float* p = W + (size_t)(k0 + kk) * ldW + col0;
            v.x = p[n];
            v.y = (n + 1 < C) ? p[n + 1] : 0.f;
            v.z = (n + 2 < C) ? p[n + 2] : 0.f;
          }
        }
        *(float4*)&Bs[kk][cn] = v;
      }
    }
    __syncthreads();

    int kmax = min(BK, K - k0);
    for (int kk = 0; kk < kmax; kk++) {
      float4 a0 = *(const float4*)&As[kk][ty * 4];
      float4 a1 = *(const float4*)&As[kk][64 + ty * 4];
      float4 b0 = *(const float4*)&Bs[kk][tx * 4];
      float4 b1 = *(const float4*)&Bs[kk][64 + tx * 4];
      float af0[4] = {a0.x, a0.y, a0.z, a0.w};
      float af1[4] = {a1.x, a1.y, a1.z, a1.w};
      float bf0[4] = {b0.x, b0.y, b0.z, b0.w};
      float bf1[4] = {b1.x, b1.y, b1.z, b1.w};
#pragma unroll
      for (int i = 0; i < 4; i++)
#pragma unroll
        for (int j = 0; j < 4; j++) {
          acc00[i][j] += af0[i] * bf0[j];
          acc01[i][j] += af0[i] * bf1[j];
          acc10[i][j] += af1[i] * bf0[j];
          acc11[i][j] += af1[i] * bf1[j];
        }
    }
    __syncthreads();
  }

#pragma unroll
  for (int ma = 0; ma < 2; ma++) {
#pragma unroll
    for (int i = 0; i < 4; i++) {
      int m = m0 + ma * 64 + ty * 4 + i;
      if (m >= M) continue;
#pragma unroll
      for (int nb = 0; nb < 2; nb++) {
        int n = n0 + nb * 64 + tx * 4;
        float (*blk)[4] = (ma == 0) ? ((nb == 0) ? acc00 : acc01)
                                    : ((nb == 0) ? acc10 : acc11);
        if (n + 3 < C) {
          float4 bv = *(const float4*)(bias + col0 + n);
          float4 o = make_float4(blk[i][0] + bv.x, blk[i][1] + bv.y,
                                 blk[i][2] + bv.z, blk[i][3] + bv.w);
          *(float4*)(out + (size_t)m * C + n) = o;
        } else {
#pragma unroll
          for (int j = 0; j < 4; j++)
            if (n + j < C) out[(size_t)m * C + n + j] = blk[i][j] + bias[col0 + n + j];
        }
      }
    }
  }
}

// ---------------- logits: one wave per sorted edge, float4 ----------------

__global__ __launch_bounds__(256) void logits_kernel(const int* __restrict__ col_src,
                                                     const int* __restrict__ col_dst,
                                                     const float* __restrict__ xl,
                                                     const float* __restrict__ xr,
                                                     const float* __restrict__ att,
                                                     float* __restrict__ ebuf, int Etot, int C) {
  int e = blockIdx.x * 4 + (threadIdx.x >> 6);
  int lane = threadIdx.x & 63;
  if (e >= Etot) return;
  int src = col_src[e], dst = col_dst[e];
  const float* pl = xl + (size_t)src * C;
  const float* pr = xr + (size_t)dst * C;
  int C4 = C >> 2;
  float sum = 0.f;
  for (int c4 = lane; c4 < C4; c4 += 64) {
    int c = c4 * 4;
    float4 l4 = *(const float4*)(pl + c);
    float4 r4 = *(const float4*)(pr + c);
    float4 a4 = *(const float4*)(att + c);
    float v;
    v = l4.x + r4.x; v = (v >= 0.f) ? v : SLOPE_ATT * v; sum += a4.x * v;
    v = l4.y + r4.y; v = (v >= 0.f) ? v : SLOPE_ATT * v; sum += a4.y * v;
    v = l4.z + r4.z; v = (v >= 0.f) ? v : SLOPE_ATT * v; sum += a4.z * v;
    v = l4.w + r4.w; v = (v >= 0.f) ? v : SLOPE_ATT * v; sum += a4.w * v;
  }
#pragma unroll
  for (int off = 32; off; off >>= 1) sum += __shfl_down(sum, off, 64);
  if (lane == 0) ebuf[e] = sum;
}

// ---------------- fused edge-softmax + aggregation: block per node ----------------

#define MAXE 2048

__global__ __launch_bounds__(256) void smax_agg_kernel(const int* __restrict__ row_ptr,
                                                       const int* __restrict__ col_src,
                                                       const float* __restrict__ ebuf,
                                                       const float* __restrict__ xl,
                                                       float* __restrict__ acc,
                                                       int C, int head) {
  int node = blockIdx.x;
  int s = row_ptr[node], t = row_ptr[node + 1];
  int deg = t - s;
  bool fast = (deg <= MAXE);

  __shared__ float sa[MAXE];
  __shared__ int ss[MAXE];
  __shared__ float rbuf[8];

  int tid = threadIdx.x;
  int wave = tid >> 6, lane = tid & 63;

  float m = -1e30f;
  for (int j = s + tid; j < t; j += 256) m = fmaxf(m, ebuf[j]);
#pragma unroll
  for (int off = 32; off; off >>= 1) m = fmaxf(m, __shfl_down(m, off, 64));
  if (lane == 0) rbuf[wave] = m;
  __syncthreads();
  m = fmaxf(fmaxf(rbuf[0], rbuf[1]), fmaxf(rbuf[2], rbuf[3]));

  float den = 0.f;
  for (int j = s + tid; j < t; j += 256) {
    float p = expf(ebuf[j] - m);
    den += p;
    if (fast) { sa[j - s] = p; ss[j - s] = col_src[j]; }
  }
#pragma unroll
  for (int off = 32; off; off >>= 1) den += __shfl_down(den, off, 64);
  if (lane == 0) rbuf[4 + wave] = den;
  __syncthreads();
  den = (rbuf[4] + rbuf[5]) + (rbuf[6] + rbuf[7]);
  float inv = 1.0f / den;

  for (int c = tid; c < C; c += 256) {
    float sum = 0.f;
    if (fast) {
      for (int jj = 0; jj < deg; jj++)
        sum += sa[jj] * xl[(size_t)ss[jj] * C + c];
    } else {
      for (int j = s; j < t; j++)
        sum += expf(ebuf[j] - m) * xl[(size_t)col_src[j] * C + c];
    }
    float val = sum * inv;
    size_t o = (size_t)node * C + c;
    acc[o] = (head == 0) ? val : acc[o] + val;
  }
}

// ---------------- finalize ----------------

__global__ __launch_bounds__(256) void finalize_kernel(const float* __restrict__ acc,
                                                       const float* __restrict__ bias,
                                                       float* __restrict__ out,
                                                       int total, int C, int apply_act) {
  int i = blockIdx.x * 256 + threadIdx.x;
  if (i >= total) return;
  int c = i % C;
  float v = acc[i] * (1.0f / 32.0f) + bias[c];
  if (apply_act) v = (v >= 0.f) ? v : SLOPE_ACT * v;
  out[i] = v;
}

// ---------------- host ----------------

static inline size_t align16(size_t x) { return (x + 15) & ~size_t(15); }

extern "C" void kernel_launch(void* const* d_in, const int* in_sizes, int n_in,
                              void* d_out, int out_size, void* d_ws, size_t ws_size,
                              hipStream_t stream) {
  const float* x0 = (const float*)d_in[0];
  const int* ei = (const int*)d_in[1];

  const int N = in_sizes[0] / 4;      // 10000
  const int E = in_sizes[1] / 2;      // 160000
  const int ETOT = E + N;             // 170000
  const int MTILES = (N + 127) / 128; // 79
  const int MPAD = MTILES * 128;      // 10112

  struct LayerP { const float *Wl, *bl, *Wr, *br, *att, *bias; int fi, fo; };
  LayerP L[3] = {
      {(const float*)d_in[2],  (const float*)d_in[3],  (const float*)d_in[4],
       (const float*)d_in[5],  (const float*)d_in[6],  (const float*)d_in[7],  4, 128},
      {(const float*)d_in[8],  (const float*)d_in[9],  (const float*)d_in[10],
       (const float*)d_in[11], (const float*)d_in[12], (const float*)d_in[13], 128, 512},
      {(const float*)d_in[14], (const float*)d_in[15], (const float*)d_in[16],
       (const float*)d_in[17], (const float*)d_in[18], (const float*)d_in[19], 512, 1028},
  };

  char* w = (char*)d_ws;
  auto alloc = [&](size_t bytes) { char* p = w; w += align16(bytes); return p; };
  int* counts   = (int*)alloc((size_t)N * 4);
  int* row_ptr  = (int*)alloc((size_t)(N + 1) * 4);
  int* cursor   = (int*)alloc((size_t)N * 4);
  int* col_src  = (int*)alloc((size_t)ETOT * 4);
  int* col_dst  = (int*)alloc((size_t)ETOT * 4);
  float* ebuf   = (float*)alloc((size_t)ETOT * 4);
  float* xlh    = (float*)alloc((size_t)N * 1028 * 4);
  float* xrh    = (float*)alloc((size_t)N * 1028 * 4);
  float* h1     = (float*)alloc((size_t)N * 128 * 4);
  float* h2     = (float*)alloc((size_t)N * 512 * 4);
  float* acc12  = (float*)alloc((size_t)N * 512 * 4);
  bf16_t* xph   = (bf16_t*)alloc((size_t)MPAD * 512 * 2);
  bf16_t* xpl   = (bf16_t*)alloc((size_t)MPAD * 512 * 2);

  // ---- CSR build (dst-sorted) ----
  init_counts_kernel<<<(N + 255) / 256, 256, 0, stream>>>(counts, N);
  count_kernel<<<(E + 255) / 256, 256, 0, stream>>>(ei + E, counts, E);
  scan_kernel<<<1, 1024, 0, stream>>>(counts, row_ptr, cursor, N);
  scatter_edges_kernel<<<(E + 255) / 256, 256, 0, stream>>>(ei, cursor, col_src, col_dst, E);
  scatter_loops_kernel<<<(N + 255) / 256, 256, 0, stream>>>(cursor, col_src, col_dst, N);

  const float* x_in[3] = {x0, h1, h2};
  float* layer_out[3]  = {h1, h2, (float*)d_out};
  float* layer_acc[3]  = {acc12, acc12, (float*)d_out};

  for (int l = 0; l < 3; l++) {
    int fi = L[l].fi, C = L[l].fo, ldW = HEADS * C;
    float* acc = layer_acc[l];
    dim3 ggrid((C + 127) / 128, MTILES, 2);

    if (l > 0) {
      int total = MPAD * (fi >> 3);
      cvt_pack_kernel<<<(total + 255) / 256, 256, 0, stream>>>(x_in[l], xph, xpl, N, MPAD, fi);
    }

    for (int h = 0; h < HEADS; h++) {
      int col0 = h * C;
      if (l == 0) {
        gemm128<<<ggrid, 256, 0, stream>>>(x_in[l], L[l].Wl, L[l].Wr, L[l].bl, L[l].br,
                                           xlh, xrh, N, fi, C, ldW, col0);
      } else {
        gemm_mfma<<<ggrid, 256, 0, stream>>>(xph, xpl, L[l].Wl, L[l].Wr, L[l].bl, L[l].br,
                                             xlh, xrh, N, fi, C, ldW, col0);
      }
      logits_kernel<<<(ETOT + 3) / 4, 256, 0, stream>>>(col_src, col_dst, xlh, xrh,
                                                        L[l].att + (size_t)h * C, ebuf, ETOT, C);
      smax_agg_kernel<<<N, 256, 0, stream>>>(row_ptr, col_src, ebuf, xlh, acc, C, h);
    }
    finalize_kernel<<<((size_t)N * C + 255) / 256, 256, 0, stream>>>(acc, L[l].bias, layer_out[l],
                                                                     N * C, C, l < 2 ? 1 : 0);
  }
}

// Round 4
// 10964.927 us; speedup vs baseline: 2.8778x; 1.7446x over previous
//
#include <hip/hip_runtime.h>
#include <cstddef>
#include <cstdint>

// ---------------------------------------------------------------------------
// GATv2 x3 layers. R3:
//  - one-pass fused edge kernel (online softmax per dst node, xl read once)
//  - W pre-split into frag-major bf16 hi/lo per head (GEMM k-loop = copies+MFMA)
// Layers 2-3 GEMM: split-bf16 MFMA (hi*hi + hi*lo + lo*hi), fp32 accum.
// Layer 1 (K=4) stays on the fp32 128x128 GEMM.
// ---------------------------------------------------------------------------

#define HEADS 32
#define SLOPE_ATT 0.2f
#define SLOPE_ACT 0.01f

typedef __bf16 bf16_t;
typedef __bf16 bf16x8 __attribute__((ext_vector_type(8)));
typedef float f32x16 __attribute__((ext_vector_type(16)));

// ---------------- CSR build ----------------

__global__ __launch_bounds__(256) void init_counts_kernel(int* counts, int n) {
  int i = blockIdx.x * 256 + threadIdx.x;
  if (i < n) counts[i] = 1;  // self-loop
}

__global__ __launch_bounds__(256) void count_kernel(const int* __restrict__ dst, int* counts, int E) {
  int e = blockIdx.x * 256 + threadIdx.x;
  if (e < E) atomicAdd(&counts[dst[e]], 1);
}

__global__ __launch_bounds__(1024) void scan_kernel(const int* __restrict__ counts,
                                                    int* __restrict__ row_ptr,
                                                    int* __restrict__ cursor, int n) {
  __shared__ int sums[1024];
  int t = threadIdx.x;
  int per = (n + 1023) >> 10;
  int base = t * per;
  int s = 0;
  for (int i = 0; i < per; i++) { int idx = base + i; if (idx < n) s += counts[idx]; }
  sums[t] = s;
  __syncthreads();
  for (int off = 1; off < 1024; off <<= 1) {
    int v = (t >= off) ? sums[t - off] : 0;
    __syncthreads();
    sums[t] += v;
    __syncthreads();
  }
  int run = (t == 0) ? 0 : sums[t - 1];
  for (int i = 0; i < per; i++) {
    int idx = base + i;
    if (idx < n) { row_ptr[idx] = run; cursor[idx] = run; run += counts[idx]; }
  }
  if (t == 1023) row_ptr[n] = sums[1023];
}

__global__ __launch_bounds__(256) void scatter_edges_kernel(const int* __restrict__ ei, int* cursor,
                                                            int* col_src, int* col_dst, int E) {
  int e = blockIdx.x * 256 + threadIdx.x;
  if (e >= E) return;
  int src = ei[e], dst = ei[E + e];
  int pos = atomicAdd(&cursor[dst], 1);
  col_src[pos] = src;
  col_dst[pos] = dst;
}

__global__ __launch_bounds__(256) void scatter_loops_kernel(int* cursor, int* col_src, int* col_dst, int N) {
  int nid = blockIdx.x * 256 + threadIdx.x;
  if (nid >= N) return;
  int pos = atomicAdd(&cursor[nid], 1);
  col_src[pos] = nid;
  col_dst[pos] = nid;
}

// ---------------- split-bf16 pack: X[M,K] fp32 -> frag-major hi/lo ----------------
// index: (mtile*(K/8) + kchunk)*1024 + mlocal*8 + (k&7); Mpad = mtiles*128.

__global__ __launch_bounds__(256) void cvt_pack_kernel(const float* __restrict__ X,
                                                       bf16_t* __restrict__ hi,
                                                       bf16_t* __restrict__ lo,
                                                       int M, int Mpad, int K) {
  int t = blockIdx.x * 256 + threadIdx.x;
  int kchunks = K >> 3;
  int total = Mpad * kchunks;
  if (t >= total) return;
  int kc = t % kchunks;
  int m = t / kchunks;
  int mt = m >> 7, ml = m & 127;
  size_t o = ((size_t)(mt * kchunks + kc)) * 1024 + (size_t)ml * 8;
  float v[8];
  if (m < M) {
    float4 a = *(const float4*)(X + (size_t)m * K + kc * 8);
    float4 b = *(const float4*)(X + (size_t)m * K + kc * 8 + 4);
    v[0] = a.x; v[1] = a.y; v[2] = a.z; v[3] = a.w;
    v[4] = b.x; v[5] = b.y; v[6] = b.z; v[7] = b.w;
  } else {
#pragma unroll
    for (int i = 0; i < 8; i++) v[i] = 0.f;
  }
  union { bf16_t h[8]; float4 f; } uh, ul;
#pragma unroll
  for (int i = 0; i < 8; i++) {
    bf16_t h = (bf16_t)v[i];
    uh.h[i] = h;
    ul.h[i] = (bf16_t)(v[i] - (float)h);
  }
  *(float4*)(hi + o) = uh.f;
  *(float4*)(lo + o) = ul.f;
}

// ---------------- W pack: per-head slice -> frag-major bf16 hi/lo ----------------
// B index: (ntile*(K/8) + kchunk)*1024 + nlocal*8 + (k&7); Npad = ntiles*128.

__global__ __launch_bounds__(256) void pack_w_kernel(const float* __restrict__ Wl,
                                                     const float* __restrict__ Wr,
                                                     bf16_t* __restrict__ hL, bf16_t* __restrict__ lL,
                                                     bf16_t* __restrict__ hR, bf16_t* __restrict__ lR,
                                                     int K, int C, int Npad, int ldW, int col0) {
  int side = blockIdx.y;
  const float* W = side ? Wr : Wl;
  bf16_t* Hi = side ? hR : hL;
  bf16_t* Lo = side ? lR : lL;
  int kchunks = K >> 3;
  int total = Npad * kchunks;
  int t = blockIdx.x * 256 + threadIdx.x;
  if (t >= total) return;
  int n = t % Npad, kc = t / Npad;
  int nt = n >> 7, nl = n & 127;
  size_t o = ((size_t)(nt * kchunks + kc)) * 1024 + (size_t)nl * 8;
  union { bf16_t h[8]; float4 f; } uh, ul;
#pragma unroll
  for (int kk = 0; kk < 8; kk++) {
    int k = kc * 8 + kk;
    float v = (n < C) ? W[(size_t)k * ldW + col0 + n] : 0.f;
    bf16_t h = (bf16_t)v;
    uh.h[kk] = h;
    ul.h[kk] = (bf16_t)(v - (float)h);
  }
  *(float4*)(Hi + o) = uh.f;
  *(float4*)(Lo + o) = ul.f;
}

// ---------------- MFMA GEMM 128x128, 256 thr, split-bf16, pre-packed A and B ----

__global__ __launch_bounds__(256) void gemm_mfma(const bf16_t* __restrict__ Xh,
                                                 const bf16_t* __restrict__ Xl,
                                                 const bf16_t* __restrict__ BhL,
                                                 const bf16_t* __restrict__ BlL,
                                                 const bf16_t* __restrict__ BhR,
                                                 const bf16_t* __restrict__ BlR,
                                                 const float* __restrict__ bl,
                                                 const float* __restrict__ br,
                                                 float* __restrict__ outL,
                                                 float* __restrict__ outR,
                                                 int M, int K, int C, int col0) {
  const bf16_t* Bh = blockIdx.z ? BhR : BhL;
  const bf16_t* Bl = blockIdx.z ? BlR : BlL;
  const float* bias = blockIdx.z ? br : bl;
  float* out = blockIdx.z ? outR : outL;

  __shared__ __align__(16) bf16_t AsH[4 * 128 * 8];
  __shared__ __align__(16) bf16_t AsL[4 * 128 * 8];
  __shared__ __align__(16) bf16_t BsH[4 * 128 * 8];
  __shared__ __align__(16) bf16_t BsL[4 * 128 * 8];

  int tid = threadIdx.x;
  int wave = tid >> 6, lane = tid & 63;
  int l31 = lane & 31, lhalf = lane >> 5;
  int mt = blockIdx.y;
  int ntb = blockIdx.x * 128;
  int m0 = mt * 128;
  int kchunks = K >> 3;

  const bf16_t* Ah = Xh + (size_t)mt * K * 128;
  const bf16_t* Al = Xl + (size_t)mt * K * 128;
  const bf16_t* Bhp = Bh + (size_t)blockIdx.x * kchunks * 1024;
  const bf16_t* Blp = Bl + (size_t)blockIdx.x * kchunks * 1024;

  f32x16 acc[4];
  for (int i = 0; i < 4; i++)
    for (int r = 0; r < 16; r++) acc[i][r] = 0.f;

  for (int k0 = 0; k0 < K; k0 += 32) {
    // A + B staging: 4 chunks x 128 rows x 8 bf16 (16B frags), coalesced copies
#pragma unroll
    for (int r = 0; r < 2; r++) {
      int a = tid + 256 * r;
      int c = a >> 7, mA = a & 127;
      size_t off = ((size_t)((k0 >> 3) + c)) * 1024 + (size_t)mA * 8;
      int li = (c * 128 + mA) * 8;
      *(float4*)&AsH[li] = *(const float4*)(Ah + off);
      *(float4*)&AsL[li] = *(const float4*)(Al + off);
      *(float4*)&BsH[li] = *(const float4*)(Bhp + off);
      *(float4*)&BsL[li] = *(const float4*)(Blp + off);
    }
    __syncthreads();

    // compute: 2 k16-steps, wave owns 32-row band, 4 n-tiles of 32
#pragma unroll
    for (int s = 0; s < 2; s++) {
      int c = s * 2 + lhalf;
      int abase = (c * 128 + wave * 32 + l31) * 8;
      bf16x8 ah = *(const bf16x8*)&AsH[abase];
      bf16x8 al = *(const bf16x8*)&AsL[abase];
#pragma unroll
      for (int nt = 0; nt < 4; nt++) {
        int bbase = (c * 128 + nt * 32 + l31) * 8;
        bf16x8 bh = *(const bf16x8*)&BsH[bbase];
        bf16x8 blo = *(const bf16x8*)&BsL[bbase];
        acc[nt] = __builtin_amdgcn_mfma_f32_32x32x16_bf16(ah, bh, acc[nt], 0, 0, 0);
        acc[nt] = __builtin_amdgcn_mfma_f32_32x32x16_bf16(ah, blo, acc[nt], 0, 0, 0);
        acc[nt] = __builtin_amdgcn_mfma_f32_32x32x16_bf16(al, bh, acc[nt], 0, 0, 0);
      }
    }
    __syncthreads();
  }

  // epilogue: C/D layout col=lane&31, row=(r&3)+8*(r>>2)+4*(lane>>5)
#pragma unroll
  for (int nt = 0; nt < 4; nt++) {
    int n = ntb + nt * 32 + l31;
    if (n >= C) continue;
    float bv = bias[col0 + n];
#pragma unroll
    for (int r = 0; r < 16; r++) {
      int row = (r & 3) + 8 * (r >> 2) + 4 * lhalf;
      int m = m0 + wave * 32 + row;
      if (m < M) out[(size_t)m * C + n] = acc[nt][r] + bv;
    }
  }
}

// ---------------- fp32 GEMM (layer 1, K=4) ----------------

#define BM 128
#define BN 128
#define BK 16
#define LDA (BM + 4)
#define LDB (BN + 4)

__global__ __launch_bounds__(256) void gemm128(const float* __restrict__ X,
                                               const float* __restrict__ Wl,
                                               const float* __restrict__ Wr,
                                               const float* __restrict__ bl,
                                               const float* __restrict__ br,
                                               float* __restrict__ outL,
                                               float* __restrict__ outR,
                                               int M, int K, int C, int ldW, int col0) {
  const float* W = blockIdx.z ? Wr : Wl;
  const float* bias = blockIdx.z ? br : bl;
  float* out = blockIdx.z ? outR : outL;

  __shared__ __align__(16) float As[BK][LDA];
  __shared__ __align__(16) float Bs[BK][LDB];

  int t = threadIdx.x;
  int tx = t & 15, ty = t >> 4;
  int m0 = blockIdx.y * BM, n0 = blockIdx.x * BN;

  float acc00[4][4] = {}, acc01[4][4] = {}, acc10[4][4] = {}, acc11[4][4] = {};

  for (int k0 = 0; k0 < K; k0 += BK) {
    {
      int kk = (t & 3) * 4;
#pragma unroll
      for (int p = 0; p < 2; p++) {
        int row = (t >> 2) + p * 64;
        int m = m0 + row;
        float4 v = make_float4(0.f, 0.f, 0.f, 0.f);
        if (m < M && (k0 + kk) < K)
          v = *(const float4*)(X + (size_t)m * K + k0 + kk);
        As[kk + 0][row] = v.x; As[kk + 1][row] = v.y;
        As[kk + 2][row] = v.z; As[kk + 3][row] = v.w;
      }
    }
    {
      int kk = t >> 4;
#pragma unroll
      for (int q = 0; q < 2; q++) {
        int cn = (t & 15) * 4 + q * 64;
        int n = n0 + cn;
        float4 v = make_float4(0.f, 0.f, 0.f, 0.f);
        if ((k0 + kk) < K) {
          if (n + 3 < C) {
            v = *(const float4*)(W + (size_t)(k0 + kk) * ldW + col0 + n);
          } else if (n < C) {
            const float* p = W + (size_t)(k0 + kk) * ldW + col0;
            v.x = p[n];
            v.y = (n + 1 < C) ? p[n + 1] : 0.f;
            v.z = (n + 2 < C) ? p[n + 2] : 0.f;
          }
        }
        *(float4*)&Bs[kk][cn] = v;
      }
    }
    __syncthreads();

    int kmax = min(BK, K - k0);
    for (int kk = 0; kk < kmax; kk++) {
      float4 a0 = *(const float4*)&As[kk][ty * 4];
      float4 a1 = *(const float4*)&As[kk][64 + ty * 4];
      float4 b0 = *(const float4*)&Bs[kk][tx * 4];
      float4 b1 = *(const float4*)&Bs[kk][64 + tx * 4];
      float af0[4] = {a0.x, a0.y, a0.z, a0.w};
      float af1[4] = {a1.x, a1.y, a1.z, a1.w};
      float bf0[4] = {b0.x, b0.y, b0.z, b0.w};
      float bf1[4] = {b1.x, b1.y, b1.z, b1.w};
#pragma unroll
      for (int i = 0; i < 4; i++)
#pragma unroll
        for (int j = 0; j < 4; j++) {
          acc00[i][j] += af0[i] * bf0[j];
          acc01[i][j] += af0[i] * bf1[j];
          acc10[i][j] += af1[i] * bf0[j];
          acc11[i][j] += af1[i] * bf1[j];
        }
    }
    __syncthreads();
  }

#pragma unroll
  for (int ma = 0; ma < 2; ma++) {
#pragma unroll
    for (int i = 0; i < 4; i++) {
      int m = m0 + ma * 64 + ty * 4 + i;
      if (m >= M) continue;
#pragma unroll
      for (int nb = 0; nb < 2; nb++) {
        int n = n0 + nb * 64 + tx * 4;
        float (*blk)[4] = (ma == 0) ? ((nb == 0) ? acc00 : acc01)
                                    : ((nb == 0) ? acc10 : acc11);
        if (n + 3 < C) {
          float4 bv = *(const float4*)(bias + col0 + n);
          float4 o = make_float4(blk[i][0] + bv.x, blk[i][1] + bv.y,
                                 blk[i][2] + bv.z, blk[i][3] + bv.w);
          *(float4*)(out + (size_t)m * C + n) = o;
        } else {
#pragma unroll
          for (int j = 0; j < 4; j++)
            if (n + j < C) out[(size_t)m * C + n + j] = blk[i][j] + bias[col0 + n + j];
        }
      }
    }
  }
}

// ---------------- one-pass fused edge kernel (online softmax) ----------------
// Block per dst node, 4 waves. Each wave: edges j = s+wave, step 4; keeps
// running (m, den, o[C]) in VGPRs; xl[src] read ONCE per edge. Wave states
// merged via LDS. acc accumulates the per-head result (head mean later).

template <int F4PT>
__global__ __launch_bounds__(256) void edge_fused_kernel(const int* __restrict__ row_ptr,
                                                         const int* __restrict__ col_src,
                                                         const float* __restrict__ xl,
                                                         const float* __restrict__ xr,
                                                         const float* __restrict__ att,
                                                         float* __restrict__ acc,
                                                         int C, int head) {
  int node = blockIdx.x;
  int tid = threadIdx.x;
  int wave = tid >> 6, lane = tid & 63;
  int C4 = C >> 2;
  int s = row_ptr[node], t = row_ptr[node + 1];

  __shared__ __align__(16) float4 slab[4][F4PT * 64];
  __shared__ float mred[4], dred[4];

  float4 xr4[F4PT], a4[F4PT], o4[F4PT];
  const float4* xrp = (const float4*)(xr + (size_t)node * C);
  const float4* ap = (const float4*)att;
#pragma unroll
  for (int k = 0; k < F4PT; k++) {
    int c4 = k * 64 + lane;
    bool ok = (c4 < C4);
    xr4[k] = ok ? xrp[c4] : make_float4(0.f, 0.f, 0.f, 0.f);
    a4[k] = ok ? ap[c4] : make_float4(0.f, 0.f, 0.f, 0.f);
    o4[k] = make_float4(0.f, 0.f, 0.f, 0.f);
  }
  float m = -1e30f, den = 0.f;

  for (int j = s + wave; j < t; j += 4) {
    int src = col_src[j];
    const float4* xlp = (const float4*)(xl + (size_t)src * C);
    float4 x4[F4PT];
    float e = 0.f;
#pragma unroll
    for (int k = 0; k < F4PT; k++) {
      int c4 = k * 64 + lane;
      x4[k] = (c4 < C4) ? xlp[c4] : make_float4(0.f, 0.f, 0.f, 0.f);
      float v;
      v = x4[k].x + xr4[k].x; v = fmaxf(v, 0.f) + SLOPE_ATT * fminf(v, 0.f); e += a4[k].x * v;
      v = x4[k].y + xr4[k].y; v = fmaxf(v, 0.f) + SLOPE_ATT * fminf(v, 0.f); e += a4[k].y * v;
      v = x4[k].z + xr4[k].z; v = fmaxf(v, 0.f) + SLOPE_ATT * fminf(v, 0.f); e += a4[k].z * v;
      v = x4[k].w + xr4[k].w; v = fmaxf(v, 0.f) + SLOPE_ATT * fminf(v, 0.f); e += a4[k].w * v;
    }
#pragma unroll
    for (int off = 1; off < 64; off <<= 1) e += __shfl_xor(e, off, 64);

    if (e <= m) {  // wave-uniform branch (e identical across lanes)
      float p = expf(e - m);
      den += p;
#pragma unroll
      for (int k = 0; k < F4PT; k++) {
        o4[k].x += p * x4[k].x; o4[k].y += p * x4[k].y;
        o4[k].z += p * x4[k].z; o4[k].w += p * x4[k].w;
      }
    } else {
      float scale = expf(m - e);  // m=-1e30 first time -> 0
      den = den * scale + 1.f;
#pragma unroll
      for (int k = 0; k < F4PT; k++) {
        o4[k].x = o4[k].x * scale + x4[k].x; o4[k].y = o4[k].y * scale + x4[k].y;
        o4[k].z = o4[k].z * scale + x4[k].z; o4[k].w = o4[k].w * scale + x4[k].w;
      }
      m = e;
    }
  }

  // merge the 4 wave states
  if (lane == 0) { mred[wave] = m; dred[wave] = den; }
  __syncthreads();
  float M2 = fmaxf(fmaxf(mred[0], mred[1]), fmaxf(mred[2], mred[3]));
  float dtot = dred[0] * expf(mred[0] - M2) + dred[1] * expf(mred[1] - M2) +
               dred[2] * expf(mred[2] - M2) + dred[3] * expf(mred[3] - M2);
  float f = expf(m - M2);
#pragma unroll
  for (int k = 0; k < F4PT; k++) {
    float4 w4 = make_float4(o4[k].x * f, o4[k].y * f, o4[k].z * f, o4[k].w * f);
    slab[wave][k * 64 + lane] = w4;
  }
  __syncthreads();
  float inv = 1.0f / dtot;
  float4* accp = (float4*)(acc + (size_t)node * C);
  for (int c4 = tid; c4 < C4; c4 += 256) {
    float4 s0 = slab[0][c4], s1 = slab[1][c4], s2 = slab[2][c4], s3 = slab[3][c4];
    float4 val = make_float4(((s0.x + s1.x) + (s2.x + s3.x)) * inv,
                             ((s0.y + s1.y) + (s2.y + s3.y)) * inv,
                             ((s0.z + s1.z) + (s2.z + s3.z)) * inv,
                             ((s0.w + s1.w) + (s2.w + s3.w)) * inv);
    if (head == 0) {
      accp[c4] = val;
    } else {
      float4 prev = accp[c4];
      accp[c4] = make_float4(prev.x + val.x, prev.y + val.y, prev.z + val.z, prev.w + val.w);
    }
  }
}

// ---------------- finalize: mean over heads + bias (+ leaky relu) ----------------

__global__ __launch_bounds__(256) void finalize_kernel(const float* __restrict__ acc,
                                                       const float* __restrict__ bias,
                                                       float* __restrict__ out,
                                                       int total, int C, int apply_act) {
  int i = blockIdx.x * 256 + threadIdx.x;
  if (i >= total) return;
  int c = i % C;
  float v = acc[i] * (1.0f / 32.0f) + bias[c];
  if (apply_act) v = (v >= 0.f) ? v : SLOPE_ACT * v;
  out[i] = v;
}

// ---------------- host ----------------

static inline size_t align16(size_t x) { return (x + 15) & ~size_t(15); }

extern "C" void kernel_launch(void* const* d_in, const int* in_sizes, int n_in,
                              void* d_out, int out_size, void* d_ws, size_t ws_size,
                              hipStream_t stream) {
  const float* x0 = (const float*)d_in[0];
  const int* ei = (const int*)d_in[1];

  const int N = in_sizes[0] / 4;      // 10000
  const int E = in_sizes[1] / 2;      // 160000
  const int ETOT = E + N;             // 170000
  const int MTILES = (N + 127) / 128; // 79
  const int MPAD = MTILES * 128;      // 10112

  struct LayerP { const float *Wl, *bl, *Wr, *br, *att, *bias; int fi, fo; };
  LayerP L[3] = {
      {(const float*)d_in[2],  (const float*)d_in[3],  (const float*)d_in[4],
       (const float*)d_in[5],  (const float*)d_in[6],  (const float*)d_in[7],  4, 128},
      {(const float*)d_in[8],  (const float*)d_in[9],  (const float*)d_in[10],
       (const float*)d_in[11], (const float*)d_in[12], (const float*)d_in[13], 128, 512},
      {(const float*)d_in[14], (const float*)d_in[15], (const float*)d_in[16],
       (const float*)d_in[17], (const float*)d_in[18], (const float*)d_in[19], 512, 1028},
  };

  char* w = (char*)d_ws;
  auto alloc = [&](size_t bytes) { char* p = w; w += align16(bytes); return p; };
  int* counts   = (int*)alloc((size_t)N * 4);
  int* row_ptr  = (int*)alloc((size_t)(N + 1) * 4);
  int* cursor   = (int*)alloc((size_t)N * 4);
  int* col_src  = (int*)alloc((size_t)ETOT * 4);
  int* col_dst  = (int*)alloc((size_t)ETOT * 4);
  float* xlh    = (float*)alloc((size_t)N * 1028 * 4);
  float* xrh    = (float*)alloc((size_t)N * 1028 * 4);
  float* h1     = (float*)alloc((size_t)N * 128 * 4);
  float* h2     = (float*)alloc((size_t)N * 512 * 4);
  float* acc12  = (float*)alloc((size_t)N * 512 * 4);
  bf16_t* xph   = (bf16_t*)alloc((size_t)MPAD * 512 * 2);
  bf16_t* xpl   = (bf16_t*)alloc((size_t)MPAD * 512 * 2);
  // per-head packed W (max: layer 3, Npad=1152, K=512)
  const size_t WPK = (size_t)1152 * 512;
  bf16_t* wphL  = (bf16_t*)alloc(WPK * 2);
  bf16_t* wplL  = (bf16_t*)alloc(WPK * 2);
  bf16_t* wphR  = (bf16_t*)alloc(WPK * 2);
  bf16_t* wplR  = (bf16_t*)alloc(WPK * 2);

  // ---- CSR build (dst-sorted) ----
  init_counts_kernel<<<(N + 255) / 256, 256, 0, stream>>>(counts, N);
  count_kernel<<<(E + 255) / 256, 256, 0, stream>>>(ei + E, counts, E);
  scan_kernel<<<1, 1024, 0, stream>>>(counts, row_ptr, cursor, N);
  scatter_edges_kernel<<<(E + 255) / 256, 256, 0, stream>>>(ei, cursor, col_src, col_dst, E);
  scatter_loops_kernel<<<(N + 255) / 256, 256, 0, stream>>>(cursor, col_src, col_dst, N);

  const float* x_in[3] = {x0, h1, h2};
  float* layer_out[3]  = {h1, h2, (float*)d_out};
  float* layer_acc[3]  = {acc12, acc12, (float*)d_out};

  auto launch_edge = [&](int C, const float* att, float* acc, int head) {
    if (C == 128)
      edge_fused_kernel<1><<<N, 256, 0, stream>>>(row_ptr, col_src, xlh, xrh, att, acc, C, head);
    else if (C == 512)
      edge_fused_kernel<2><<<N, 256, 0, stream>>>(row_ptr, col_src, xlh, xrh, att, acc, C, head);
    else
      edge_fused_kernel<5><<<N, 256, 0, stream>>>(row_ptr, col_src, xlh, xrh, att, acc, C, head);
  };

  for (int l = 0; l < 3; l++) {
    int fi = L[l].fi, C = L[l].fo, ldW = HEADS * C;
    int ntiles = (C + 127) / 128, Npad = ntiles * 128;
    float* acc = layer_acc[l];

    if (l > 0) {
      int total = MPAD * (fi >> 3);
      cvt_pack_kernel<<<(total + 255) / 256, 256, 0, stream>>>(x_in[l], xph, xpl, N, MPAD, fi);
    }

    for (int h = 0; h < HEADS; h++) {
      int col0 = h * C;
      if (l == 0) {
        dim3 ggrid(ntiles, MTILES, 2);
        gemm128<<<ggrid, 256, 0, stream>>>(x_in[l], L[l].Wl, L[l].Wr, L[l].bl, L[l].br,
                                           xlh, xrh, N, fi, C, ldW, col0);
      } else {
        int wtotal = Npad * (fi >> 3);
        dim3 wgrid((wtotal + 255) / 256, 2);
        pack_w_kernel<<<wgrid, 256, 0, stream>>>(L[l].Wl, L[l].Wr, wphL, wplL, wphR, wplR,
                                                 fi, C, Npad, ldW, col0);
        dim3 ggrid(ntiles, MTILES, 2);
        gemm_mfma<<<ggrid, 256, 0, stream>>>(xph, xpl, wphL, wplL, wphR, wplR,
                                             L[l].bl, L[l].br, xlh, xrh, N, fi, C, col0);
      }
      launch_edge(C, L[l].att + (size_t)h * C, acc, h);
    }
    finalize_kernel<<<((size_t)N * C + 255) / 256, 256, 0, stream>>>(acc, L[l].bias, layer_out[l],
                                                                     N * C, C, l < 2 ? 1 : 0);
  }
}